// Round 6
// baseline (80.216 us; speedup 1.0000x reference)
//
#include <hip/hip_runtime.h>
#include <hip/hip_fp16.h>

// CapsNet dynamic routing, two-phase, fp16 u_hat, DPP reductions.
// x: [128, 1152, 8] fp32, w: [1152, 10, 8, 16] fp32 -> v: [128, 10, 16] fp32
// Phase 1: u_hat[b][j][i][m] (fp16) -> d_ws  (R4-exact).
// Phase 2: routing, 192 thr / IPT 6, u held as __half2 regs (low VGPR,
//          4 waves/SIMD, single occupancy pass), iter-0 specialized.

#define NB 128
#define NI 1152
#define NJ 10
#define ID 8
#define OD 16

// ---- DPP wave-64 sum (rocPRIM pattern): full sum lands in lane 63 ----
template<int ctrl, int rmask, int bmask>
__device__ __forceinline__ float dpp_add(float x) {
    int y = __builtin_amdgcn_update_dpp(0, __builtin_bit_cast(int, x),
                                        ctrl, rmask, bmask, false);
    return x + __builtin_bit_cast(float, y);
}
__device__ __forceinline__ float wave_sum63(float x) {
    x = dpp_add<0x111, 0xf, 0xf>(x);  // row_shr:1
    x = dpp_add<0x112, 0xf, 0xf>(x);  // row_shr:2
    x = dpp_add<0x114, 0xf, 0xe>(x);  // row_shr:4
    x = dpp_add<0x118, 0xf, 0xc>(x);  // row_shr:8
    x = dpp_add<0x142, 0xa, 0xf>(x);  // row_bcast:15
    x = dpp_add<0x143, 0xc, 0xf>(x);  // row_bcast:31
    return x;                          // lane 63 = sum of all 64 lanes
}

// ---------------- Phase 1: u_hat[b][j][i][m] (fp16) — R4 exact ----------------
__global__ __launch_bounds__(256) void uhat_kernel(
    const float* __restrict__ x, const float* __restrict__ w,
    __half* __restrict__ uhat)
{
    __shared__ float xl[16 * 640];  // [b][i] rows of 8 floats, stride 10 (40 KB)
    const int t  = threadIdx.x;
    const int i0 = blockIdx.x * 64;
    const int b0 = blockIdx.y * 16;
    const int j  = blockIdx.z;

    #pragma unroll
    for (int c = 0; c < 8; ++c) {
        const int h  = t + 256 * c;        // 0..2047
        const int bb = h >> 7;
        const int ii = (h >> 1) & 63;
        const int nh = h & 1;
        const float4 xv4 = *(const float4*)(
            x + ((size_t)(b0 + bb) * NI + (i0 + ii)) * ID + nh * 4);
        float* dst = &xl[bb * 640 + ii * 10 + nh * 4];
        dst[0] = xv4.x; dst[1] = xv4.y; dst[2] = xv4.z; dst[3] = xv4.w;
    }

    const int lane = t & 63;
    const int il   = (t >> 6) * 16 + (lane >> 2);  // local i (0..63)
    const int i    = i0 + il;
    const int mq   = lane & 3;                     // m-quarter

    const float* wp = w + ((size_t)i * NJ + j) * (ID * OD) + mq * 4;
    float wr[8][4];
    #pragma unroll
    for (int n = 0; n < 8; ++n)
        *(float4*)wr[n] = *(const float4*)(wp + n * OD);

    __syncthreads();

    for (int bb = 0; bb < 16; ++bb) {
        const float* xr = &xl[bb * 640 + il * 10];
        float xv[ID];
        #pragma unroll
        for (int q = 0; q < 4; ++q) { xv[2*q] = xr[2*q]; xv[2*q+1] = xr[2*q+1]; }
        float a0 = 0.f, a1 = 0.f, a2 = 0.f, a3 = 0.f;
        #pragma unroll
        for (int n = 0; n < ID; ++n) {
            a0 = fmaf(xv[n], wr[n][0], a0);
            a1 = fmaf(xv[n], wr[n][1], a1);
            a2 = fmaf(xv[n], wr[n][2], a2);
            a3 = fmaf(xv[n], wr[n][3], a3);
        }
        __half2 h01 = __floats2half2_rn(a0, a1);
        __half2 h23 = __floats2half2_rn(a2, a3);
        uint2 st;
        st.x = *(unsigned int*)&h01;
        st.y = *(unsigned int*)&h23;
        __half* up = uhat + (((size_t)(b0 + bb) * NJ + j) * NI + i) * OD + mq * 4;
        *(uint2*)up = st;  // wave: 16 i x 32B = 512B contiguous
    }
}

// ---------------- Phase 2: routing with u in __half2 registers ----------------
#define P2T 192
#define P2I 6
#define P2NW (P2T / 64)

__global__ __launch_bounds__(P2T, 4) void route_kernel(
    const __half* __restrict__ uhat, float* __restrict__ out)
{
    const int t = threadIdx.x;
    const int b = blockIdx.x & (NB - 1);
    const int j = blockIdx.x >> 7;

    const __half* upb = uhat + ((size_t)b * NJ + j) * NI * OD;

    // u stays packed: 48 VGPRs total; all 12 loads issued up-front
    __half2 uh[P2I][8];
    #pragma unroll
    for (int k = 0; k < P2I; ++k) {
        const __half* p = upb + (size_t)(t + k * P2T) * OD;
        *(float4*)&uh[k][0] = *(const float4*)(p);
        *(float4*)&uh[k][4] = *(const float4*)(p + 8);
    }

    __shared__ float4 red4[P2NW][5];
    const int wavei = t >> 6;
    const int lane  = t & 63;

    float logit[P2I];
    #pragma unroll
    for (int k = 0; k < P2I; ++k) logit[k] = 0.0f;
    float v[OD];

    // ---- iter 0: c uniform = 1/1152 exactly -> plain sum, no exp, no denom ----
    {
        float acc[OD];
        #pragma unroll
        for (int m = 0; m < OD; ++m) acc[m] = 0.0f;
        #pragma unroll
        for (int k = 0; k < P2I; ++k) {
            #pragma unroll
            for (int q = 0; q < 8; ++q) {
                const float2 f = __half22float2(uh[k][q]);
                acc[2*q]   += f.x;
                acc[2*q+1] += f.y;
            }
        }
        #pragma unroll
        for (int m = 0; m < OD; ++m) acc[m] = wave_sum63(acc[m]);
        if (lane == 63) {
            red4[wavei][0] = make_float4(acc[0],  acc[1],  acc[2],  acc[3]);
            red4[wavei][1] = make_float4(acc[4],  acc[5],  acc[6],  acc[7]);
            red4[wavei][2] = make_float4(acc[8],  acc[9],  acc[10], acc[11]);
            red4[wavei][3] = make_float4(acc[12], acc[13], acc[14], acc[15]);
        }
        __syncthreads();
        float tot[OD];
        #pragma unroll
        for (int g = 0; g < 4; ++g) {
            float4 sum = red4[0][g];
            #pragma unroll
            for (int wv = 1; wv < P2NW; ++wv) {
                float4 r = red4[wv][g];
                sum.x += r.x; sum.y += r.y; sum.z += r.z; sum.w += r.w;
            }
            tot[4*g+0] = sum.x; tot[4*g+1] = sum.y;
            tot[4*g+2] = sum.z; tot[4*g+3] = sum.w;
        }
        const float inv_den = (1.0f / 1152.0f);
        float s2 = 0.0f;
        float sv[OD];
        #pragma unroll
        for (int m = 0; m < OD; ++m) {
            sv[m] = tot[m] * inv_den;
            s2 = fmaf(sv[m], sv[m], s2);
        }
        const float scale = (s2 / (1.0f + s2)) / sqrtf(s2 + 1e-8f);
        #pragma unroll
        for (int m = 0; m < OD; ++m) v[m] = scale * sv[m];
        // logit update (v . u_i), fp16 operand folded via fma_mix
        #pragma unroll
        for (int k = 0; k < P2I; ++k) {
            float a = 0.0f;
            #pragma unroll
            for (int q = 0; q < 8; ++q) {
                a = fmaf(v[2*q],   __low2float(uh[k][q]),  a);
                a = fmaf(v[2*q+1], __high2float(uh[k][q]), a);
            }
            logit[k] += a;
        }
    }

    // ---- iters 1,2: deferred-normalization softmax ----
    for (int it = 1; it < 3; ++it) {
        float acc[OD + 1];
        #pragma unroll
        for (int q = 0; q <= OD; ++q) acc[q] = 0.0f;
        #pragma unroll
        for (int k = 0; k < P2I; ++k) {
            const float c = __expf(logit[k]);
            acc[OD] += c;
            #pragma unroll
            for (int q = 0; q < 8; ++q) {
                acc[2*q]   = fmaf(c, __low2float(uh[k][q]),  acc[2*q]);
                acc[2*q+1] = fmaf(c, __high2float(uh[k][q]), acc[2*q+1]);
            }
        }
        #pragma unroll
        for (int q = 0; q <= OD; ++q) acc[q] = wave_sum63(acc[q]);

        __syncthreads();   // prev-iter red4 reads complete
        if (lane == 63) {
            red4[wavei][0] = make_float4(acc[0],  acc[1],  acc[2],  acc[3]);
            red4[wavei][1] = make_float4(acc[4],  acc[5],  acc[6],  acc[7]);
            red4[wavei][2] = make_float4(acc[8],  acc[9],  acc[10], acc[11]);
            red4[wavei][3] = make_float4(acc[12], acc[13], acc[14], acc[15]);
            red4[wavei][4] = make_float4(acc[16], 0.f, 0.f, 0.f);
        }
        __syncthreads();

        float tot[OD + 1];
        #pragma unroll
        for (int g = 0; g < 5; ++g) {
            float4 sum = red4[0][g];
            #pragma unroll
            for (int wv = 1; wv < P2NW; ++wv) {
                float4 r = red4[wv][g];
                sum.x += r.x; sum.y += r.y; sum.z += r.z; sum.w += r.w;
            }
            if (g < 4) {
                tot[4*g+0] = sum.x; tot[4*g+1] = sum.y;
                tot[4*g+2] = sum.z; tot[4*g+3] = sum.w;
            } else {
                tot[OD] = sum.x;
            }
        }
        const float inv_den = 1.0f / tot[OD];
        float s2 = 0.0f;
        float sv[OD];
        #pragma unroll
        for (int m = 0; m < OD; ++m) {
            sv[m] = tot[m] * inv_den;
            s2 = fmaf(sv[m], sv[m], s2);
        }
        const float scale = (s2 / (1.0f + s2)) / sqrtf(s2 + 1e-8f);
        #pragma unroll
        for (int m = 0; m < OD; ++m) v[m] = scale * sv[m];

        if (it == 1) {
            #pragma unroll
            for (int k = 0; k < P2I; ++k) {
                float a = 0.0f;
                #pragma unroll
                for (int q = 0; q < 8; ++q) {
                    a = fmaf(v[2*q],   __low2float(uh[k][q]),  a);
                    a = fmaf(v[2*q+1], __high2float(uh[k][q]), a);
                }
                logit[k] += a;
            }
        }
    }

    if (t < OD) out[((size_t)b * NJ + j) * OD + t] = v[t];
}

// ---------------- Fallback: fully fused fp32 (if d_ws too small) ----------------
template<int NT, int IPTT>
__device__ __forceinline__ void route_core(float (&u)[IPTT][OD], int t, int b, int j,
                                           float* __restrict__ out)
{
    constexpr int NW = NT / 64;
    __shared__ float4 red4[NW][5];
    const int wavei = t >> 6;
    const int lane  = t & 63;

    float logit[IPTT];
    #pragma unroll
    for (int k = 0; k < IPTT; ++k) logit[k] = 0.0f;
    float v[OD];

    for (int iter = 0; iter < 3; ++iter) {
        float acc[OD + 1];
        #pragma unroll
        for (int q = 0; q <= OD; ++q) acc[q] = 0.0f;
        #pragma unroll
        for (int k = 0; k < IPTT; ++k) {
            const float c = __expf(logit[k]);
            acc[OD] += c;
            #pragma unroll
            for (int m = 0; m < OD; ++m) acc[m] = fmaf(c, u[k][m], acc[m]);
        }
        #pragma unroll
        for (int q = 0; q <= OD; ++q) acc[q] = wave_sum63(acc[q]);

        if (iter != 0) __syncthreads();
        if (lane == 63) {
            red4[wavei][0] = make_float4(acc[0],  acc[1],  acc[2],  acc[3]);
            red4[wavei][1] = make_float4(acc[4],  acc[5],  acc[6],  acc[7]);
            red4[wavei][2] = make_float4(acc[8],  acc[9],  acc[10], acc[11]);
            red4[wavei][3] = make_float4(acc[12], acc[13], acc[14], acc[15]);
            red4[wavei][4] = make_float4(acc[16], 0.f, 0.f, 0.f);
        }
        __syncthreads();

        float tot[OD + 1];
        #pragma unroll
        for (int g = 0; g < 5; ++g) {
            float4 sum = red4[0][g];
            #pragma unroll
            for (int wv = 1; wv < NW; ++wv) {
                float4 r = red4[wv][g];
                sum.x += r.x; sum.y += r.y; sum.z += r.z; sum.w += r.w;
            }
            if (g < 4) {
                tot[4*g+0] = sum.x; tot[4*g+1] = sum.y;
                tot[4*g+2] = sum.z; tot[4*g+3] = sum.w;
            } else {
                tot[OD] = sum.x;
            }
        }

        const float inv_den = 1.0f / tot[OD];
        float s2 = 0.0f;
        float sv[OD];
        #pragma unroll
        for (int m = 0; m < OD; ++m) {
            sv[m] = tot[m] * inv_den;
            s2 = fmaf(sv[m], sv[m], s2);
        }
        const float scale = (s2 / (1.0f + s2)) / sqrtf(s2 + 1e-8f);
        #pragma unroll
        for (int m = 0; m < OD; ++m) v[m] = scale * sv[m];

        if (iter < 2) {
            #pragma unroll
            for (int k = 0; k < IPTT; ++k) {
                float a = 0.0f;
                #pragma unroll
                for (int m = 0; m < OD; ++m) a = fmaf(v[m], u[k][m], a);
                logit[k] += a;
            }
        }
    }
    if (t < OD) out[((size_t)b * NJ + j) * OD + t] = v[t];
}

__global__ __launch_bounds__(P2T) void fused_kernel(
    const float* __restrict__ x, const float* __restrict__ w,
    float* __restrict__ out)
{
    const int t = threadIdx.x;
    const int b = blockIdx.x & (NB - 1);
    const int j = blockIdx.x >> 7;

    float u[P2I][OD];
    #pragma unroll
    for (int k = 0; k < P2I; ++k) {
        const int i = t + k * P2T;
        const float* xp = x + ((size_t)b * NI + i) * ID;
        float xv[ID];
        const float4 x0 = *(const float4*)(xp);
        const float4 x1 = *(const float4*)(xp + 4);
        xv[0]=x0.x; xv[1]=x0.y; xv[2]=x0.z; xv[3]=x0.w;
        xv[4]=x1.x; xv[5]=x1.y; xv[6]=x1.z; xv[7]=x1.w;
        const float* wp = w + ((size_t)i * NJ + j) * (ID * OD);
        #pragma unroll
        for (int m = 0; m < OD; ++m) u[k][m] = 0.0f;
        #pragma unroll
        for (int n = 0; n < ID; ++n) {
            float wrow[OD];
            *(float4*)(wrow + 0)  = *(const float4*)(wp + n * OD + 0);
            *(float4*)(wrow + 4)  = *(const float4*)(wp + n * OD + 4);
            *(float4*)(wrow + 8)  = *(const float4*)(wp + n * OD + 8);
            *(float4*)(wrow + 12) = *(const float4*)(wp + n * OD + 12);
            const float xn = xv[n];
            #pragma unroll
            for (int m = 0; m < OD; ++m) u[k][m] = fmaf(xn, wrow[m], u[k][m]);
        }
    }
    route_core<P2T, P2I>(u, t, b, j, out);
}

extern "C" void kernel_launch(void* const* d_in, const int* in_sizes, int n_in,
                              void* d_out, int out_size, void* d_ws, size_t ws_size,
                              hipStream_t stream) {
    const float* x = (const float*)d_in[2];
    const float* w = (const float*)d_in[3];
    float* out = (float*)d_out;

    const size_t UHAT_BYTES = (size_t)NB * NJ * NI * OD * sizeof(__half); // ~47.2 MB

    if (ws_size >= UHAT_BYTES) {
        __half* uhat = (__half*)d_ws;
        hipLaunchKernelGGL(uhat_kernel, dim3(NI / 64, NB / 16, NJ), dim3(256),
                           0, stream, x, w, uhat);
        hipLaunchKernelGGL(route_kernel, dim3(NB * NJ), dim3(P2T),
                           0, stream, uhat, out);
    } else {
        hipLaunchKernelGGL(fused_kernel, dim3(NB * NJ), dim3(P2T),
                           0, stream, x, w, out);
    }
}

// Round 7
// 40.472 us; speedup vs baseline: 1.9820x; 1.9820x over previous
//
#include <hip/hip_runtime.h>
#include <hip/hip_fp16.h>

// CapsNet dynamic routing, two-phase, fp16 u_hat, DPP reductions.
// x: [128, 1152, 8] fp32, w: [1152, 10, 8, 16] fp32 -> v: [128, 10, 16] fp32
// Phase 1: u_hat[b][j][i][m] (fp16) -> d_ws  (R4-exact, ~10 us, near store floor).
// Phase 2: routing, 192 thr / IPT 6, u kept PACKED as __half2 (48 VGPR persistent,
//          all loads issued before first use; extracts fold to v_fma_mix_f32).

#define NB 128
#define NI 1152
#define NJ 10
#define ID 8
#define OD 16

// ---- DPP wave-64 sum (rocPRIM pattern): full sum lands in lane 63 ----
template<int ctrl, int rmask, int bmask>
__device__ __forceinline__ float dpp_add(float x) {
    int y = __builtin_amdgcn_update_dpp(0, __builtin_bit_cast(int, x),
                                        ctrl, rmask, bmask, false);
    return x + __builtin_bit_cast(float, y);
}
__device__ __forceinline__ float wave_sum63(float x) {
    x = dpp_add<0x111, 0xf, 0xf>(x);  // row_shr:1
    x = dpp_add<0x112, 0xf, 0xf>(x);  // row_shr:2
    x = dpp_add<0x114, 0xf, 0xe>(x);  // row_shr:4
    x = dpp_add<0x118, 0xf, 0xc>(x);  // row_shr:8
    x = dpp_add<0x142, 0xa, 0xf>(x);  // row_bcast:15
    x = dpp_add<0x143, 0xc, 0xf>(x);  // row_bcast:31
    return x;                          // lane 63 = sum of all 64 lanes
}

// ---------------- Phase 1: u_hat[b][j][i][m] (fp16) — R4 exact ----------------
__global__ __launch_bounds__(256) void uhat_kernel(
    const float* __restrict__ x, const float* __restrict__ w,
    __half* __restrict__ uhat)
{
    __shared__ float xl[16 * 640];  // [b][i] rows of 8 floats, stride 10 (40 KB)
    const int t  = threadIdx.x;
    const int i0 = blockIdx.x * 64;
    const int b0 = blockIdx.y * 16;
    const int j  = blockIdx.z;

    #pragma unroll
    for (int c = 0; c < 8; ++c) {
        const int h  = t + 256 * c;        // 0..2047
        const int bb = h >> 7;
        const int ii = (h >> 1) & 63;
        const int nh = h & 1;
        const float4 xv4 = *(const float4*)(
            x + ((size_t)(b0 + bb) * NI + (i0 + ii)) * ID + nh * 4);
        float* dst = &xl[bb * 640 + ii * 10 + nh * 4];
        dst[0] = xv4.x; dst[1] = xv4.y; dst[2] = xv4.z; dst[3] = xv4.w;
    }

    const int lane = t & 63;
    const int il   = (t >> 6) * 16 + (lane >> 2);  // local i (0..63)
    const int i    = i0 + il;
    const int mq   = lane & 3;                     // m-quarter

    const float* wp = w + ((size_t)i * NJ + j) * (ID * OD) + mq * 4;
    float wr[8][4];
    #pragma unroll
    for (int n = 0; n < 8; ++n)
        *(float4*)wr[n] = *(const float4*)(wp + n * OD);

    __syncthreads();

    for (int bb = 0; bb < 16; ++bb) {
        const float* xr = &xl[bb * 640 + il * 10];
        float xv[ID];
        #pragma unroll
        for (int q = 0; q < 4; ++q) { xv[2*q] = xr[2*q]; xv[2*q+1] = xr[2*q+1]; }
        float a0 = 0.f, a1 = 0.f, a2 = 0.f, a3 = 0.f;
        #pragma unroll
        for (int n = 0; n < ID; ++n) {
            a0 = fmaf(xv[n], wr[n][0], a0);
            a1 = fmaf(xv[n], wr[n][1], a1);
            a2 = fmaf(xv[n], wr[n][2], a2);
            a3 = fmaf(xv[n], wr[n][3], a3);
        }
        __half2 h01 = __floats2half2_rn(a0, a1);
        __half2 h23 = __floats2half2_rn(a2, a3);
        uint2 st;
        st.x = *(unsigned int*)&h01;
        st.y = *(unsigned int*)&h23;
        __half* up = uhat + (((size_t)(b0 + bb) * NJ + j) * NI + i) * OD + mq * 4;
        *(uint2*)up = st;  // wave: 16 i x 32B = 512B contiguous
    }
}

// ---------------- Phase 2: routing, u packed as __half2 ----------------
#define P2T 192
#define P2I 6
#define P2NW (P2T / 64)

__global__ __launch_bounds__(P2T) void route_kernel(
    const __half* __restrict__ uhat, float* __restrict__ out)
{
    const int t = threadIdx.x;
    const int b = blockIdx.x & (NB - 1);
    const int j = blockIdx.x >> 7;

    const __half* upb = uhat + ((size_t)b * NJ + j) * NI * OD;

    // All 12 loads issued before first use; u stays packed (48 VGPRs).
    __half2 uh[P2I][8];
    #pragma unroll
    for (int k = 0; k < P2I; ++k) {
        const __half* p = upb + (size_t)(t + k * P2T) * OD;
        *(float4*)&uh[k][0] = *(const float4*)(p);
        *(float4*)&uh[k][4] = *(const float4*)(p + 8);
    }

    __shared__ float4 red4[P2NW][5];
    const int wavei = t >> 6;
    const int lane  = t & 63;

    float logit[P2I];
    #pragma unroll
    for (int k = 0; k < P2I; ++k) logit[k] = 0.0f;
    float v[OD];

    for (int iter = 0; iter < 3; ++iter) {
        // deferred-normalization softmax accumulators
        float acc[OD + 1];
        #pragma unroll
        for (int q = 0; q <= OD; ++q) acc[q] = 0.0f;
        #pragma unroll
        for (int k = 0; k < P2I; ++k) {
            const float c = __expf(logit[k]);
            acc[OD] += c;
            #pragma unroll
            for (int q = 0; q < 8; ++q) {
                acc[2*q]   = fmaf(c, __low2float(uh[k][q]),  acc[2*q]);
                acc[2*q+1] = fmaf(c, __high2float(uh[k][q]), acc[2*q+1]);
            }
        }
        // 17 wave sums, pure VALU (no LDS pipe)
        #pragma unroll
        for (int q = 0; q <= OD; ++q) acc[q] = wave_sum63(acc[q]);

        if (iter != 0) __syncthreads();   // prev-iter red4 reads complete
        if (lane == 63) {
            red4[wavei][0] = make_float4(acc[0],  acc[1],  acc[2],  acc[3]);
            red4[wavei][1] = make_float4(acc[4],  acc[5],  acc[6],  acc[7]);
            red4[wavei][2] = make_float4(acc[8],  acc[9],  acc[10], acc[11]);
            red4[wavei][3] = make_float4(acc[12], acc[13], acc[14], acc[15]);
            red4[wavei][4] = make_float4(acc[16], 0.f, 0.f, 0.f);
        }
        __syncthreads();

        float tot[OD + 1];
        #pragma unroll
        for (int g = 0; g < 5; ++g) {
            float4 sum = red4[0][g];
            #pragma unroll
            for (int wv = 1; wv < P2NW; ++wv) {
                float4 r = red4[wv][g];
                sum.x += r.x; sum.y += r.y; sum.z += r.z; sum.w += r.w;
            }
            if (g < 4) {
                tot[4*g+0] = sum.x; tot[4*g+1] = sum.y;
                tot[4*g+2] = sum.z; tot[4*g+3] = sum.w;
            } else {
                tot[OD] = sum.x;
            }
        }

        const float inv_den = 1.0f / tot[OD];
        float s2 = 0.0f;
        float sv[OD];
        #pragma unroll
        for (int m = 0; m < OD; ++m) {
            sv[m] = tot[m] * inv_den;
            s2 = fmaf(sv[m], sv[m], s2);
        }
        const float scale = (s2 / (1.0f + s2)) / sqrtf(s2 + 1e-8f);
        #pragma unroll
        for (int m = 0; m < OD; ++m) v[m] = scale * sv[m];

        if (iter < 2) {
            #pragma unroll
            for (int k = 0; k < P2I; ++k) {
                float a = 0.0f;
                #pragma unroll
                for (int q = 0; q < 8; ++q) {
                    a = fmaf(v[2*q],   __low2float(uh[k][q]),  a);
                    a = fmaf(v[2*q+1], __high2float(uh[k][q]), a);
                }
                logit[k] += a;
            }
        }
    }

    if (t < OD) out[((size_t)b * NJ + j) * OD + t] = v[t];
}

// ---------------- Fallback: fully fused fp32 (if d_ws too small) ----------------
template<int NT, int IPTT>
__device__ __forceinline__ void route_core(float (&u)[IPTT][OD], int t, int b, int j,
                                           float* __restrict__ out)
{
    constexpr int NW = NT / 64;
    __shared__ float4 red4[NW][5];
    const int wavei = t >> 6;
    const int lane  = t & 63;

    float logit[IPTT];
    #pragma unroll
    for (int k = 0; k < IPTT; ++k) logit[k] = 0.0f;
    float v[OD];

    for (int iter = 0; iter < 3; ++iter) {
        float acc[OD + 1];
        #pragma unroll
        for (int q = 0; q <= OD; ++q) acc[q] = 0.0f;
        #pragma unroll
        for (int k = 0; k < IPTT; ++k) {
            const float c = __expf(logit[k]);
            acc[OD] += c;
            #pragma unroll
            for (int m = 0; m < OD; ++m) acc[m] = fmaf(c, u[k][m], acc[m]);
        }
        #pragma unroll
        for (int q = 0; q <= OD; ++q) acc[q] = wave_sum63(acc[q]);

        if (iter != 0) __syncthreads();
        if (lane == 63) {
            red4[wavei][0] = make_float4(acc[0],  acc[1],  acc[2],  acc[3]);
            red4[wavei][1] = make_float4(acc[4],  acc[5],  acc[6],  acc[7]);
            red4[wavei][2] = make_float4(acc[8],  acc[9],  acc[10], acc[11]);
            red4[wavei][3] = make_float4(acc[12], acc[13], acc[14], acc[15]);
            red4[wavei][4] = make_float4(acc[16], 0.f, 0.f, 0.f);
        }
        __syncthreads();

        float tot[OD + 1];
        #pragma unroll
        for (int g = 0; g < 5; ++g) {
            float4 sum = red4[0][g];
            #pragma unroll
            for (int wv = 1; wv < NW; ++wv) {
                float4 r = red4[wv][g];
                sum.x += r.x; sum.y += r.y; sum.z += r.z; sum.w += r.w;
            }
            if (g < 4) {
                tot[4*g+0] = sum.x; tot[4*g+1] = sum.y;
                tot[4*g+2] = sum.z; tot[4*g+3] = sum.w;
            } else {
                tot[OD] = sum.x;
            }
        }

        const float inv_den = 1.0f / tot[OD];
        float s2 = 0.0f;
        float sv[OD];
        #pragma unroll
        for (int m = 0; m < OD; ++m) {
            sv[m] = tot[m] * inv_den;
            s2 = fmaf(sv[m], sv[m], s2);
        }
        const float scale = (s2 / (1.0f + s2)) / sqrtf(s2 + 1e-8f);
        #pragma unroll
        for (int m = 0; m < OD; ++m) v[m] = scale * sv[m];

        if (iter < 2) {
            #pragma unroll
            for (int k = 0; k < IPTT; ++k) {
                float a = 0.0f;
                #pragma unroll
                for (int m = 0; m < OD; ++m) a = fmaf(v[m], u[k][m], a);
                logit[k] += a;
            }
        }
    }
    if (t < OD) out[((size_t)b * NJ + j) * OD + t] = v[t];
}

__global__ __launch_bounds__(P2T) void fused_kernel(
    const float* __restrict__ x, const float* __restrict__ w,
    float* __restrict__ out)
{
    const int t = threadIdx.x;
    const int b = blockIdx.x & (NB - 1);
    const int j = blockIdx.x >> 7;

    float u[P2I][OD];
    #pragma unroll
    for (int k = 0; k < P2I; ++k) {
        const int i = t + k * P2T;
        const float* xp = x + ((size_t)b * NI + i) * ID;
        float xv[ID];
        const float4 x0 = *(const float4*)(xp);
        const float4 x1 = *(const float4*)(xp + 4);
        xv[0]=x0.x; xv[1]=x0.y; xv[2]=x0.z; xv[3]=x0.w;
        xv[4]=x1.x; xv[5]=x1.y; xv[6]=x1.z; xv[7]=x1.w;
        const float* wp = w + ((size_t)i * NJ + j) * (ID * OD);
        #pragma unroll
        for (int m = 0; m < OD; ++m) u[k][m] = 0.0f;
        #pragma unroll
        for (int n = 0; n < ID; ++n) {
            float wrow[OD];
            *(float4*)(wrow + 0)  = *(const float4*)(wp + n * OD + 0);
            *(float4*)(wrow + 4)  = *(const float4*)(wp + n * OD + 4);
            *(float4*)(wrow + 8)  = *(const float4*)(wp + n * OD + 8);
            *(float4*)(wrow + 12) = *(const float4*)(wp + n * OD + 12);
            const float xn = xv[n];
            #pragma unroll
            for (int m = 0; m < OD; ++m) u[k][m] = fmaf(xn, wrow[m], u[k][m]);
        }
    }
    route_core<P2T, P2I>(u, t, b, j, out);
}

extern "C" void kernel_launch(void* const* d_in, const int* in_sizes, int n_in,
                              void* d_out, int out_size, void* d_ws, size_t ws_size,
                              hipStream_t stream) {
    const float* x = (const float*)d_in[2];
    const float* w = (const float*)d_in[3];
    float* out = (float*)d_out;

    const size_t UHAT_BYTES = (size_t)NB * NJ * NI * OD * sizeof(__half); // ~47.2 MB

    if (ws_size >= UHAT_BYTES) {
        __half* uhat = (__half*)d_ws;
        hipLaunchKernelGGL(uhat_kernel, dim3(NI / 64, NB / 16, NJ), dim3(256),
                           0, stream, x, w, uhat);
        hipLaunchKernelGGL(route_kernel, dim3(NB * NJ), dim3(P2T),
                           0, stream, uhat, out);
    } else {
        hipLaunchKernelGGL(fused_kernel, dim3(NB * NJ), dim3(P2T),
                           0, stream, x, w, out);
    }
}